// Round 3
// baseline (92.696 us; speedup 1.0000x reference)
//
#include <hip/hip_runtime.h>
#include <stdint.h>

#define N_COLS 256
#define M_ROWS 65536
#define DIM    512
#define MT     64              // m per k1 block
#define NBM    (M_ROWS / MT)   // 1024
#define TOPK   10
#define NEG_INIT (-3.0e38f)
#define PS     12              // part stride (floats)
#define BK     32
#define STAGES (DIM / BK)      // 16

typedef float  f32x4  __attribute__((ext_vector_type(4)));
typedef short  bf16x8 __attribute__((ext_vector_type(8)));
typedef short  bf16x4 __attribute__((ext_vector_type(4)));

__device__ __forceinline__ unsigned short f2bf(float x) {
    union { float f; unsigned u; } v; v.f = x;
    unsigned r = v.u + 0x7fffu + ((v.u >> 16) & 1u);   // RNE
    return (unsigned short)(r >> 16);
}
__device__ __forceinline__ float bf2f(unsigned short h) {
    union { float f; unsigned u; } v; v.u = ((unsigned)h) << 16; return v.f;
}
__device__ __forceinline__ bf16x8 cvt8(float4 a, float4 b) {
    bf16x8 r;
    r[0] = (short)f2bf(a.x); r[1] = (short)f2bf(a.y);
    r[2] = (short)f2bf(a.z); r[3] = (short)f2bf(a.w);
    r[4] = (short)f2bf(b.x); r[5] = (short)f2bf(b.y);
    r[6] = (short)f2bf(b.z); r[7] = (short)f2bf(b.w);
    return r;
}
__device__ __forceinline__ void gload16(const void* g, void* l) {
    __builtin_amdgcn_global_load_lds(
        (const __attribute__((address_space(1))) void*)g,
        (__attribute__((address_space(3))) void*)l, 16, 0, 0);
}

// K0: colm f32 -> bf16 (row-major, once).
__global__ __launch_bounds__(256)
void k0_cvt(const float* __restrict__ colm, unsigned short* __restrict__ colmbf) {
    int i = (blockIdx.x * 256 + threadIdx.x) * 8;
    float4 a = *reinterpret_cast<const float4*>(colm + i);
    float4 b = *reinterpret_cast<const float4*>(colm + i + 4);
    *reinterpret_cast<bf16x8*>(colmbf + i) = cvt8(a, b);
}

// K1: block bm computes sim[0:256][bm*64:+64]; A via global_load_lds (pre-swizzled
// source), B reg-staged f32->bf16; fused top-10 + pos-stats epilogue.
__global__ __launch_bounds__(256, 3)
void k1_mfma(const unsigned short* __restrict__ colmbf, const int* __restrict__ clab_g,
             const float* __restrict__ rowm, const int* __restrict__ rlab_g,
             float* __restrict__ part) {
    __shared__ __align__(16) char smem[40960];   // A: 2x16KB @0, B: 2x4KB @32768; sim aliases 0..32767
    __shared__ int rlabS[MT];

    const int t  = threadIdx.x, bm = blockIdx.x;
    const int jm0 = bm * MT;
    const int w = t >> 6, l = t & 63, lr = l & 15, lq = l >> 4;

    if (t < MT) rlabS[t] = rlab_g[jm0 + t];
    const int clab_n = clab_g[t];

    // --- A gload constants: 4 calls/wave, each 64 granules of 16B ---
    // LDS granule idx = call*64 + lane -> (row = idx>>2, slot g' = idx&3);
    // global k-chunk g = g' ^ ((row>>1)&3)  (involution; makes frag ds_read 2-way max)
    int rowOffA[4];
#pragma unroll
    for (int i = 0; i < 4; ++i) {
        int row = (w * 4 + i) * 16 + (l >> 2);
        int g   = (l & 3) ^ ((l >> 3) & 3);
        rowOffA[i] = row * DIM + g * 8;          // element offset, + k0 per stage
    }

    // --- B staging constants: thread t owns (row=t>>2, k-chunk g=t&3), 8 f32 ---
    const int brow  = t >> 2, bg = t & 3;
    const int bWoff = ((brow * 4) + (bg ^ ((t >> 3) & 3))) * 16;        // LDS byte in B buf
    const size_t gB = (size_t)(jm0 + brow) * DIM + bg * 8;              // rowm element offset

    // --- fragment-read constants ---
    const int gslot = lq ^ ((lr >> 1) & 3);
    int aOff[4], bOff[4];
#pragma unroll
    for (int i = 0; i < 4; ++i) {
        aOff[i] = (w * 64 + i * 16 + lr) * 64 + gslot * 16;   // bytes in A buf
        bOff[i] = (i * 16 + lr) * 64 + gslot * 16;            // bytes in B buf
    }

    f32x4 acc[4][4];
#pragma unroll
    for (int ni = 0; ni < 4; ++ni)
#pragma unroll
        for (int mj = 0; mj < 4; ++mj) acc[ni][mj] = (f32x4){0.f, 0.f, 0.f, 0.f};

    // prologue: stage 0 -> buf 0
#pragma unroll
    for (int i = 0; i < 4; ++i)
        gload16(colmbf + rowOffA[i], (void*)(smem + (w * 4 + i) * 1024));
    {
        float4 b0 = *reinterpret_cast<const float4*>(rowm + gB);
        float4 b1 = *reinterpret_cast<const float4*>(rowm + gB + 4);
        *reinterpret_cast<bf16x8*>(smem + 32768 + bWoff) = cvt8(b0, b1);
    }
    __syncthreads();

#pragma unroll 2
    for (int s = 0; s < STAGES; ++s) {
        const int cur = s & 1, nxt = cur ^ 1;
        float4 nb0, nb1;
        if (s < STAGES - 1) {
            const int k0 = (s + 1) * BK;
#pragma unroll
            for (int i = 0; i < 4; ++i)
                gload16(colmbf + rowOffA[i] + k0,
                        (void*)(smem + nxt * 16384 + (w * 4 + i) * 1024));
            nb0 = *reinterpret_cast<const float4*>(rowm + gB + k0);
            nb1 = *reinterpret_cast<const float4*>(rowm + gB + k0 + 4);
        }
        bf16x8 aF[4], bF[4];
        const char* aB = smem + cur * 16384;
        const char* bB = smem + 32768 + cur * 4096;
#pragma unroll
        for (int ni = 0; ni < 4; ++ni) aF[ni] = *reinterpret_cast<const bf16x8*>(aB + aOff[ni]);
#pragma unroll
        for (int mj = 0; mj < 4; ++mj) bF[mj] = *reinterpret_cast<const bf16x8*>(bB + bOff[mj]);
#pragma unroll
        for (int ni = 0; ni < 4; ++ni)
#pragma unroll
            for (int mj = 0; mj < 4; ++mj)
                acc[ni][mj] = __builtin_amdgcn_mfma_f32_16x16x32_bf16(
                    aF[ni], bF[mj], acc[ni][mj], 0, 0, 0);
        if (s < STAGES - 1)
            *reinterpret_cast<bf16x8*>(smem + 32768 + nxt * 4096 + bWoff) = cvt8(nb0, nb1);
        __syncthreads();
    }

    // ---- epilogue: acc -> swizzled bf16 sim[m][n] in LDS (32KB), then scan ----
#pragma unroll
    for (int ni = 0; ni < 4; ++ni)
#pragma unroll
        for (int mj = 0; mj < 4; ++mj) {
            int m  = mj * 16 + lr;
            int n0 = w * 64 + ni * 16 + lq * 4;
            bf16x4 p;
            p[0] = (short)f2bf(acc[ni][mj][0]); p[1] = (short)f2bf(acc[ni][mj][1]);
            p[2] = (short)f2bf(acc[ni][mj][2]); p[3] = (short)f2bf(acc[ni][mj][3]);
            int byte = m * 512 + (((n0 >> 2) ^ (m & 7)) * 8);
            *reinterpret_cast<bf16x4*>(smem + byte) = p;
        }
    __syncthreads();

    float tk[TOPK];
#pragma unroll
    for (int r = 0; r < TOPK; ++r) tk[r] = NEG_INIT;
    float psum = 0.f; int pcnt = 0;
    const int nswz = t >> 2, nlo = (t & 3) * 2;
#pragma unroll 4
    for (int m = 0; m < MT; ++m) {
        int byte = m * 512 + ((nswz ^ (m & 7)) * 8) + nlo;
        float s  = bf2f(*reinterpret_cast<const unsigned short*>(smem + byte));
        int lab  = rlabS[m];
        if (lab == clab_n) {
            if (s < 0.99999f) { psum += 1.0f - s; pcnt += 1; }
        } else if (s > tk[TOPK - 1]) {
            float v = s;
#pragma unroll
            for (int r = 0; r < TOPK; ++r) {
                float old = tk[r]; bool gt = v > old;
                tk[r] = gt ? v : old; v = gt ? old : v;
            }
        }
    }
    float* wp = part + ((size_t)t * NBM + bm) * PS;
#pragma unroll
    for (int r = 0; r < TOPK; ++r) wp[r] = tk[r];
    wp[10] = psum;
    wp[11] = (float)pcnt;
}

__device__ __forceinline__ void merge2(float* o, const float* a, const float* b) {
    int ia = 0, ib = 0;
#pragma unroll
    for (int r = 0; r < TOPK; ++r) {
        float va = a[ia], vb = b[ib];
        bool ta = va >= vb;
        o[r] = ta ? va : vb;
        ia += ta; ib += !ta;
    }
}

// K2: one block per col; thread t pre-merges 4 of the 1024 partial lists, then
// pointer-walk top-10 over the 256 merged lists + pos reduce -> per-col loss.
__global__ __launch_bounds__(256)
void k2_merge(const float* __restrict__ part, float* __restrict__ colloss) {
    __shared__ float vs[256 * TOPK];
    __shared__ float rv[256];
    __shared__ int   ri[256];
    const int c = blockIdx.x, t = threadIdx.x;

    float L0[TOPK], L1[TOPK], L2[TOPK], L3[TOPK];
    float ps = 0.f, pc = 0.f;
    {
        const float* w0 = part + ((size_t)c * NBM + t) * PS;
        const float* w1 = part + ((size_t)c * NBM + t + 256) * PS;
        const float* w2 = part + ((size_t)c * NBM + t + 512) * PS;
        const float* w3 = part + ((size_t)c * NBM + t + 768) * PS;
#pragma unroll
        for (int r = 0; r < TOPK; ++r) { L0[r] = w0[r]; L1[r] = w1[r]; L2[r] = w2[r]; L3[r] = w3[r]; }
        ps = w0[10] + w1[10] + w2[10] + w3[10];
        pc = w0[11] + w1[11] + w2[11] + w3[11];
    }
    float m01[TOPK], m23[TOPK], mm[TOPK];
    merge2(m01, L0, L1); merge2(m23, L2, L3); merge2(mm, m01, m23);
#pragma unroll
    for (int r = 0; r < TOPK; ++r) vs[t * TOPK + r] = mm[r];

    rv[t] = ps; __syncthreads();
    for (int s = 128; s > 0; s >>= 1) { if (t < s) rv[t] += rv[t + s]; __syncthreads(); }
    float ps_tot = rv[0]; __syncthreads();
    rv[t] = pc; __syncthreads();
    for (int s = 128; s > 0; s >>= 1) { if (t < s) rv[t] += rv[t + s]; __syncthreads(); }
    float pc_tot = rv[0]; __syncthreads();

    int p = 0;
    float cand = vs[t * TOPK];
    float negsum = 0.f;
    for (int r = 0; r < TOPK; ++r) {
        rv[t] = cand; ri[t] = t; __syncthreads();
        for (int s = 128; s > 0; s >>= 1) {
            if (t < s && rv[t + s] > rv[t]) { rv[t] = rv[t + s]; ri[t] = ri[t + s]; }
            __syncthreads();
        }
        negsum += rv[0];
        if (t == ri[0]) { ++p; cand = (p < TOPK) ? vs[t * TOPK + p] : NEG_INIT; }
        __syncthreads();
    }

    if (t == 0) {
        float pos_loss = (pc_tot > 0.5f) ? 6.0f * ps_tot / pc_tot : 0.0f;
        colloss[c] = pos_loss + 15.0f * (negsum / (float)TOPK);
    }
}

// K3: final scalar reduce.
__global__ __launch_bounds__(256)
void k3_final(const float* __restrict__ colloss, float* __restrict__ out) {
    __shared__ float rv[256];
    const int t = threadIdx.x;
    rv[t] = colloss[t];
    __syncthreads();
    for (int s = 128; s > 0; s >>= 1) { if (t < s) rv[t] += rv[t + s]; __syncthreads(); }
    if (t == 0) out[0] = rv[0] / (float)N_COLS;
}

extern "C" void kernel_launch(void* const* d_in, const int* in_sizes, int n_in,
                              void* d_out, int out_size, void* d_ws, size_t ws_size,
                              hipStream_t stream) {
    const float* colm = (const float*)d_in[0];   // [256, 512] f32
    const int*   clab = (const int*)d_in[1];     // [256] i32
    const float* rowm = (const float*)d_in[2];   // [65536, 512] f32
    const int*   rlab = (const int*)d_in[3];     // [65536] i32

    float* part    = (float*)d_ws;                               // 256*1024*12 f32 = 12.58 MB
    float* colloss = part + (size_t)N_COLS * NBM * PS;           // 256 f32
    unsigned short* colmbf = (unsigned short*)(colloss + 256);   // 131072 bf16 = 256 KB
    float* out = (float*)d_out;

    hipLaunchKernelGGL(k0_cvt, dim3(64), dim3(256), 0, stream, colm, colmbf);
    hipLaunchKernelGGL(k1_mfma, dim3(NBM), dim3(256), 0, stream,
                       colmbf, clab, rowm, rlab, part);
    hipLaunchKernelGGL(k2_merge, dim3(N_COLS), dim3(256), 0, stream, part, colloss);
    hipLaunchKernelGGL(k3_final, dim3(1), dim3(256), 0, stream, colloss, out);
}